// Round 5
// baseline (181.512 us; speedup 1.0000x reference)
//
#include <hip/hip_runtime.h>
#include <hip/hip_fp16.h>
#include <cstdint>

#define BB 32
#define CC 256
#define HF 64
#define WF 64
#define MM 4096   // HF*WF
#define NN 64
#define MCHUNKS 32   // m-chunks per batch
#define MPB 128      // m per block (4 waves x 32)
#define KSTEPS 8     // 256 / 32
#define NBLK (BB * MCHUNKS)

typedef _Float16 half8 __attribute__((ext_vector_type(8)));
typedef __fp16 fp16x2 __attribute__((ext_vector_type(2)));
typedef float f32x4 __attribute__((ext_vector_type(4)));

// ws layout:
//   wq    : _Float16[BB * 16384]      fragment-linear q-hat      (1 MB)
//   partM : float[MCHUNKS][BB*NN]     per-(b,chunk) max          (256 KB)
//   partS : float[MCHUNKS][BB*NN]     per-(b,chunk) sumexp       (256 KB)
//   trgl  : float[BB*NN]
//   tidx  : int[BB*NN]
//   counter: int

// ---------------- phase 0: gather + l2-normalize queries ----------------
__global__ void phase0_gather_norm(const float* __restrict__ fs,
                                   const float* __restrict__ kps_src,
                                   const float* __restrict__ kps_trg,
                                   _Float16* __restrict__ wq,
                                   int* __restrict__ trgidx,
                                   int* __restrict__ counter) {
  int blk = blockIdx.x;          // b*N + n
  int b = blk >> 6, n = blk & 63;
  int c = threadIdx.x;

  if (blk == 0 && c == 0) *counter = 0;   // reset ticket every call

  float kx = kps_src[blk * 2 + 0];
  float ky = kps_src[blk * 2 + 1];
  int fx = min(max((int)(kx * (1.0f / 16.0f)), 0), WF - 1);
  int fy = min(max((int)(ky * (1.0f / 16.0f)), 0), HF - 1);
  int pix = fy * WF + fx;

  float x = fs[((size_t)b * CC + c) * MM + pix];

  float v = x * x;
  #pragma unroll
  for (int off = 32; off >= 1; off >>= 1) v += __shfl_xor(v, off);
  __shared__ float ssum[4];
  int wid = c >> 6, lane = c & 63;
  if (lane == 0) ssum[wid] = v;
  __syncthreads();
  float tot = ssum[0] + ssum[1] + ssum[2] + ssum[3];
  float inv = 1.0f / fmaxf(sqrtf(tot), 1e-12f);

  // fragment-linear layout: lane l holds frag[16-dim=l&15][k=(l>>4)*8+j]
  // index = ((ks*4+nt)*64 + lane)*8 + j
  int ks = c >> 5, kg = (c >> 3) & 3, j = c & 7;
  int nt = n >> 4, nr = n & 15;
  int lane_f = kg * 16 + nr;
  size_t off = (size_t)b * 16384 + (size_t)((ks * 4 + nt) * 64 + lane_f) * 8 + j;
  wq[off] = (_Float16)(x * inv);

  if (c == 0) {
    float tx = kps_trg[blk * 2 + 0], ty = kps_trg[blk * 2 + 1];
    int gx = min(max((int)(tx * (1.0f / 16.0f)), 0), WF - 1);
    int gy = min(max((int)(ty * (1.0f / 16.0f)), 0), HF - 1);
    trgidx[blk] = gy * WF + gx;
  }
}

__device__ __forceinline__ float agent_load(const float* p) {
  return __hip_atomic_load(p, __ATOMIC_RELAXED, __HIP_MEMORY_SCOPE_AGENT);
}

// ------- phase B: MFMA logits + softmax partials + last-block finish -----
__global__ void __launch_bounds__(256, 4)
phaseB(const float* __restrict__ ft,
       const _Float16* __restrict__ wq,
       const int* __restrict__ tidx,
       float* __restrict__ partM,
       float* __restrict__ partS,
       float* __restrict__ trgl,
       const void* __restrict__ maskp,
       float* __restrict__ out,
       int* __restrict__ counter) {
  __shared__ _Float16 qf[16384];     // 32 KB: q-hat fragments for this b
  __shared__ int trg_lds[NN];
  __shared__ float pM[4 * NN], pS[4 * NN];
  __shared__ int lastFlag;

  int b = blockIdx.x >> 5, mc = blockIdx.x & 31;
  int tid = threadIdx.x;

  const uint4* src = (const uint4*)(wq + (size_t)b * 16384);
  uint4* dst = (uint4*)qf;
  #pragma unroll
  for (int i = 0; i < 8; ++i) dst[tid + 256 * i] = src[tid + 256 * i];
  if (tid < NN) trg_lds[tid] = tidx[b * NN + tid];
  __syncthreads();

  int w = tid >> 6, lane = tid & 63, g = lane >> 4, col = lane & 15;
  int m0 = mc * MPB + w * 32;        // this wave's first m
  const float* fb = ft + (size_t)b * CC * MM;
  const float* lb0 = fb + (size_t)(g * 8) * MM + (m0 + col);  // mt=0
  const float* lb1 = lb0 + 16;                                // mt=1

  f32x4 acc[4][2];
  #pragma unroll
  for (int nt = 0; nt < 4; ++nt)
    #pragma unroll
    for (int mt = 0; mt < 2; ++mt) acc[nt][mt] = (f32x4){0.f, 0.f, 0.f, 0.f};
  float ss0 = 0.f, ss1 = 0.f;

  const half8* qv = (const half8*)qf;

  float cur0[8], cur1[8], nxt0[8], nxt1[8];
  #pragma unroll
  for (int j = 0; j < 8; ++j) {
    cur0[j] = lb0[(size_t)j * MM];
    cur1[j] = lb1[(size_t)j * MM];
  }

  #pragma unroll
  for (int ks = 0; ks < KSTEPS; ++ks) {
    if (ks + 1 < KSTEPS) {
      #pragma unroll
      for (int j = 0; j < 8; ++j) {
        nxt0[j] = lb0[(size_t)((ks + 1) * 32 + j) * MM];
        nxt1[j] = lb1[(size_t)((ks + 1) * 32 + j) * MM];
      }
    }

    half8 a0 = qv[(ks * 4 + 0) * 64 + lane];
    half8 a1 = qv[(ks * 4 + 1) * 64 + lane];
    half8 a2 = qv[(ks * 4 + 2) * 64 + lane];
    half8 a3 = qv[(ks * 4 + 3) * 64 + lane];

    half8 b0, b1;
    #pragma unroll
    for (int j = 0; j < 4; ++j) {
      ss0 += cur0[2 * j] * cur0[2 * j] + cur0[2 * j + 1] * cur0[2 * j + 1];
      ss1 += cur1[2 * j] * cur1[2 * j] + cur1[2 * j + 1] * cur1[2 * j + 1];
      fp16x2 h0 = __builtin_amdgcn_cvt_pkrtz(cur0[2 * j], cur0[2 * j + 1]);
      fp16x2 h1 = __builtin_amdgcn_cvt_pkrtz(cur1[2 * j], cur1[2 * j + 1]);
      b0[2 * j] = (_Float16)h0[0]; b0[2 * j + 1] = (_Float16)h0[1];
      b1[2 * j] = (_Float16)h1[0]; b1[2 * j + 1] = (_Float16)h1[1];
    }

    // SWAPPED operands: A = ft (rows=m), B = q (cols=n)  ->  D[m][n]
    acc[0][0] = __builtin_amdgcn_mfma_f32_16x16x32_f16(b0, a0, acc[0][0], 0, 0, 0);
    acc[1][0] = __builtin_amdgcn_mfma_f32_16x16x32_f16(b0, a1, acc[1][0], 0, 0, 0);
    acc[2][0] = __builtin_amdgcn_mfma_f32_16x16x32_f16(b0, a2, acc[2][0], 0, 0, 0);
    acc[3][0] = __builtin_amdgcn_mfma_f32_16x16x32_f16(b0, a3, acc[3][0], 0, 0, 0);
    acc[0][1] = __builtin_amdgcn_mfma_f32_16x16x32_f16(b1, a0, acc[0][1], 0, 0, 0);
    acc[1][1] = __builtin_amdgcn_mfma_f32_16x16x32_f16(b1, a1, acc[1][1], 0, 0, 0);
    acc[2][1] = __builtin_amdgcn_mfma_f32_16x16x32_f16(b1, a2, acc[2][1], 0, 0, 0);
    acc[3][1] = __builtin_amdgcn_mfma_f32_16x16x32_f16(b1, a3, acc[3][1], 0, 0, 0);

    #pragma unroll
    for (int j = 0; j < 8; ++j) { cur0[j] = nxt0[j]; cur1[j] = nxt1[j]; }
  }

  // full column sumsq (groups hold disjoint c-subsets) -> per-col total
  ss0 += __shfl_xor(ss0, 16); ss0 += __shfl_xor(ss0, 32);
  ss1 += __shfl_xor(ss1, 16); ss1 += __shfl_xor(ss1, 32);

  // lane's output m-rows are g*4+r (+ mt*16); fetch those columns' scales
  float sc0[4], sc1[4];
  #pragma unroll
  for (int r = 0; r < 4; ++r) {
    float t0 = __shfl(ss0, g * 4 + r, 16);
    float t1 = __shfl(ss1, g * 4 + r, 16);
    sc0[r] = 100.0f / fmaxf(sqrtf(t0), 1e-12f);   // 1/(||f||*T)
    sc1[r] = 100.0f / fmaxf(sqrtf(t1), 1e-12f);
  }

  #pragma unroll
  for (int nt = 0; nt < 4; ++nt) {
    int n = nt * 16 + col;           // this lane's n (fixed per lane)
    int t = trg_lds[n];
    float v[8];
    #pragma unroll
    for (int r = 0; r < 4; ++r) {
      v[r]     = acc[nt][0][r] * sc0[r];
      v[4 + r] = acc[nt][1][r] * sc1[r];
    }
    #pragma unroll
    for (int r = 0; r < 4; ++r) {     // m = m0 + mt*16 + g*4 + r
      if (t == m0 + g * 4 + r)      trgl[b * NN + n] = v[r];
      if (t == m0 + 16 + g * 4 + r) trgl[b * NN + n] = v[4 + r];
    }
    float mx = fmaxf(fmaxf(fmaxf(v[0], v[1]), fmaxf(v[2], v[3])),
                     fmaxf(fmaxf(v[4], v[5]), fmaxf(v[6], v[7])));
    mx = fmaxf(mx, __shfl_xor(mx, 16));
    mx = fmaxf(mx, __shfl_xor(mx, 32));
    float s = 0.f;
    #pragma unroll
    for (int j = 0; j < 8; ++j) s += __expf(v[j] - mx);
    s += __shfl_xor(s, 16);
    s += __shfl_xor(s, 32);
    if (g == 0) { pM[w * NN + n] = mx; pS[w * NN + n] = s; }
  }
  __syncthreads();

  if (tid < NN) {
    int n = tid;
    float gm = fmaxf(fmaxf(pM[n], pM[NN + n]), fmaxf(pM[2 * NN + n], pM[3 * NN + n]));
    float S = 0.f;
    #pragma unroll
    for (int ww = 0; ww < 4; ++ww)
      S += pS[ww * NN + n] * __expf(pM[ww * NN + n] - gm);
    partM[mc * (BB * NN) + b * NN + n] = gm;
    partS[mc * (BB * NN) + b * NN + n] = S;
  }

  // ---------------- last-block-done final reduction ----------------
  __threadfence();
  if (tid == 0) lastFlag = (atomicAdd(counter, 1) == NBLK - 1) ? 1 : 0;
  __syncthreads();
  if (!lastFlag) return;
  __threadfence();

  __shared__ int flagF, flagB;
  if (tid == 0) { flagF = 0; flagB = 0; }
  __syncthreads();
  const unsigned char* mb = (const unsigned char*)maskp;
  int lf = 0, lb = 0;
  for (int i = tid; i < BB * NN; i += 256) {
    unsigned char vch = mb[i];
    int r = i & 3;
    if (r == 3 && vch == 0x3F) lf = 1;   // float32 1.0f pattern
    if (r != 0 && vch != 0) lb = 1;      // nonzero off-word byte
  }
  if (lf) atomicOr(&flagF, 1);
  if (lb) atomicOr(&flagB, 1);
  __syncthreads();
  int layout = flagF ? 2 : (flagB ? 0 : 1);  // 2=float32, 0=uchar, 1=int32

  float lsum = 0.f, lcnt = 0.f;
  #pragma unroll
  for (int h = 0; h < 8; ++h) {
    int p = tid + h * 256;
    // online logsumexp merge over 32 chunks (single pass)
    float gm = -1e30f, S = 0.f;
    for (int c2 = 0; c2 < MCHUNKS; ++c2) {
      float mi = agent_load(&partM[c2 * (BB * NN) + p]);
      float si = agent_load(&partS[c2 * (BB * NN) + p]);
      float nm = fmaxf(gm, mi);
      S = S * __expf(gm - nm) + si * __expf(mi - nm);
      gm = nm;
    }
    float nll = gm + logf(S) - agent_load(&trgl[p]);

    float mval;
    if (layout == 2) mval = ((const float*)maskp)[p];
    else if (layout == 0) mval = (float)mb[p];
    else mval = (float)((const int*)maskp)[p];
    lsum += nll * mval;
    lcnt += mval;
  }

  #pragma unroll
  for (int off = 32; off >= 1; off >>= 1) {
    lsum += __shfl_xor(lsum, off);
    lcnt += __shfl_xor(lcnt, off);
  }
  __shared__ float sS[4], sC[4];
  int wid2 = tid >> 6, lane2 = tid & 63;
  if (lane2 == 0) { sS[wid2] = lsum; sC[wid2] = lcnt; }
  __syncthreads();
  if (tid == 0) {
    float s = sS[0] + sS[1] + sS[2] + sS[3];
    float cn = sC[0] + sC[1] + sC[2] + sC[3];
    out[0] = s / fmaxf(cn, 1.0f);
  }
}

extern "C" void kernel_launch(void* const* d_in, const int* in_sizes, int n_in,
                              void* d_out, int out_size, void* d_ws, size_t ws_size,
                              hipStream_t stream) {
  const float* fs   = (const float*)d_in[0];
  const float* ft   = (const float*)d_in[1];
  const float* ksrc = (const float*)d_in[2];
  const float* ktrg = (const float*)d_in[3];
  const void*  mask = d_in[4];
  float* out = (float*)d_out;

  _Float16* wq = (_Float16*)d_ws;                        // BB*16384 halfs
  float* partM = (float*)((char*)d_ws + (size_t)BB * 16384 * 2);
  float* partS = partM + (size_t)MCHUNKS * BB * NN;
  float* trgl  = partS + (size_t)MCHUNKS * BB * NN;
  int* tidx    = (int*)(trgl + BB * NN);
  int* counter = tidx + BB * NN;

  phase0_gather_norm<<<BB * NN, 256, 0, stream>>>(fs, ksrc, ktrg, wq, tidx, counter);
  phaseB<<<NBLK, 256, 0, stream>>>(ft, wq, tidx, partM, partS, trgl, mask, out, counter);
}

// Round 6
// 47.208 us; speedup vs baseline: 3.8449x; 3.8449x over previous
//
#include <hip/hip_runtime.h>
#include <hip/hip_fp16.h>
#include <cstdint>

#define BB 32
#define CC 256
#define HF 64
#define WF 64
#define MM 4096   // HF*WF
#define NN 64
#define MCHUNKS 32   // m-chunks per batch
#define MPB 128      // m per block (4 waves x 32)
#define KSTEPS 8     // 256 / 32
#define NBLK (BB * MCHUNKS)

typedef _Float16 half8 __attribute__((ext_vector_type(8)));
typedef __fp16 fp16x2 __attribute__((ext_vector_type(2)));
typedef float f32x4 __attribute__((ext_vector_type(4)));

// ws layout:
//   wq    : _Float16[BB * 16384]      fragment-linear q-hat      (1 MB)
//   partM : float[MCHUNKS][BB*NN]     per-(b,chunk) max          (256 KB)
//   partS : float[MCHUNKS][BB*NN]     per-(b,chunk) sumexp       (256 KB)
//   trgl  : float[BB*NN]
//   tidx  : int[BB*NN]
//   minfo : [0]=count(float), [1]=layout(int)

// ---------------- phase 0: gather + l2-normalize queries ----------------
__global__ void phase0_gather_norm(const float* __restrict__ fs,
                                   const float* __restrict__ kps_src,
                                   const float* __restrict__ kps_trg,
                                   const void* __restrict__ maskp,
                                   _Float16* __restrict__ wq,
                                   int* __restrict__ trgidx,
                                   float* __restrict__ minfoF,
                                   int* __restrict__ minfoI,
                                   float* __restrict__ out) {
  int blk = blockIdx.x;          // b*N + n
  int b = blk >> 6, n = blk & 63;
  int c = threadIdx.x;

  float kx = kps_src[blk * 2 + 0];
  float ky = kps_src[blk * 2 + 1];
  int fx = min(max((int)(kx * (1.0f / 16.0f)), 0), WF - 1);
  int fy = min(max((int)(ky * (1.0f / 16.0f)), 0), HF - 1);
  int pix = fy * WF + fx;

  float x = fs[((size_t)b * CC + c) * MM + pix];

  float v = x * x;
  #pragma unroll
  for (int off = 32; off >= 1; off >>= 1) v += __shfl_xor(v, off);
  __shared__ float ssum[4];
  int wid = c >> 6, lane = c & 63;
  if (lane == 0) ssum[wid] = v;
  __syncthreads();
  float tot = ssum[0] + ssum[1] + ssum[2] + ssum[3];
  float inv = 1.0f / fmaxf(sqrtf(tot), 1e-12f);

  // fragment-linear layout: lane l holds frag[16-dim=l&15][k=(l>>4)*8+j]
  // index = ((ks*4+nt)*64 + lane)*8 + j
  int ks = c >> 5, kg = (c >> 3) & 3, j = c & 7;
  int nt = n >> 4, nr = n & 15;
  int lane_f = kg * 16 + nr;
  size_t off = (size_t)b * 16384 + (size_t)((ks * 4 + nt) * 64 + lane_f) * 8 + j;
  wq[off] = (_Float16)(x * inv);

  if (c == 0) {
    float tx = kps_trg[blk * 2 + 0], ty = kps_trg[blk * 2 + 1];
    int gx = min(max((int)(tx * (1.0f / 16.0f)), 0), WF - 1);
    int gy = min(max((int)(ty * (1.0f / 16.0f)), 0), HF - 1);
    trgidx[blk] = gy * WF + gx;
  }

  // ---- block 0 extra: mask layout detection + count + zero out ----
  if (blk == 0) {
    __shared__ int flagF, flagB;
    if (c == 0) { flagF = 0; flagB = 0; out[0] = 0.0f; }
    __syncthreads();
    const unsigned char* mb = (const unsigned char*)maskp;
    int lf = 0, lb = 0;
    for (int i = c; i < BB * NN; i += 256) {
      unsigned char vch = mb[i];
      int r = i & 3;
      if (r == 3 && vch == 0x3F) lf = 1;   // float32 1.0f pattern
      if (r != 0 && vch != 0) lb = 1;      // nonzero off-word byte
    }
    if (lf) atomicOr(&flagF, 1);
    if (lb) atomicOr(&flagB, 1);
    __syncthreads();
    int layout = flagF ? 2 : (flagB ? 0 : 1);  // 2=float32, 0=uchar, 1=int32

    float lc = 0.f;
    for (int i = c; i < BB * NN; i += 256) {
      float mval;
      if (layout == 2) mval = ((const float*)maskp)[i];
      else if (layout == 0) mval = (float)mb[i];
      else mval = (float)((const int*)maskp)[i];
      lc += mval;
    }
    #pragma unroll
    for (int o2 = 32; o2 >= 1; o2 >>= 1) lc += __shfl_xor(lc, o2);
    __shared__ float cs[4];
    if (lane == 0) cs[wid] = lc;
    __syncthreads();
    if (c == 0) {
      minfoF[0] = cs[0] + cs[1] + cs[2] + cs[3];
      minfoI[1] = layout;
    }
  }
}

// ------- phase B: MFMA logits + per-chunk softmax partials -------------
__global__ void __launch_bounds__(256, 4)
phaseB(const float* __restrict__ ft,
       const _Float16* __restrict__ wq,
       const int* __restrict__ tidx,
       float* __restrict__ partM,
       float* __restrict__ partS,
       float* __restrict__ trgl) {
  __shared__ _Float16 qf[16384];     // 32 KB: q-hat fragments for this b
  __shared__ int trg_lds[NN];
  __shared__ float pM[4 * NN], pS[4 * NN];

  int b = blockIdx.x >> 5, mc = blockIdx.x & 31;
  int tid = threadIdx.x;

  const uint4* src = (const uint4*)(wq + (size_t)b * 16384);
  uint4* dst = (uint4*)qf;
  #pragma unroll
  for (int i = 0; i < 8; ++i) dst[tid + 256 * i] = src[tid + 256 * i];
  if (tid < NN) trg_lds[tid] = tidx[b * NN + tid];
  __syncthreads();

  int w = tid >> 6, lane = tid & 63, g = lane >> 4, col = lane & 15;
  int m0 = mc * MPB + w * 32;        // this wave's first m
  const float* fb = ft + (size_t)b * CC * MM;
  const float* lb0 = fb + (size_t)(g * 8) * MM + (m0 + col);  // mt=0
  const float* lb1 = lb0 + 16;                                // mt=1

  f32x4 acc[4][2];
  #pragma unroll
  for (int nt = 0; nt < 4; ++nt)
    #pragma unroll
    for (int mt = 0; mt < 2; ++mt) acc[nt][mt] = (f32x4){0.f, 0.f, 0.f, 0.f};
  float ss0 = 0.f, ss1 = 0.f;

  const half8* qv = (const half8*)qf;

  float cur0[8], cur1[8], nxt0[8], nxt1[8];
  #pragma unroll
  for (int j = 0; j < 8; ++j) {
    cur0[j] = lb0[(size_t)j * MM];
    cur1[j] = lb1[(size_t)j * MM];
  }

  #pragma unroll
  for (int ks = 0; ks < KSTEPS; ++ks) {
    if (ks + 1 < KSTEPS) {
      #pragma unroll
      for (int j = 0; j < 8; ++j) {
        nxt0[j] = lb0[(size_t)((ks + 1) * 32 + j) * MM];
        nxt1[j] = lb1[(size_t)((ks + 1) * 32 + j) * MM];
      }
    }

    half8 a0 = qv[(ks * 4 + 0) * 64 + lane];
    half8 a1 = qv[(ks * 4 + 1) * 64 + lane];
    half8 a2 = qv[(ks * 4 + 2) * 64 + lane];
    half8 a3 = qv[(ks * 4 + 3) * 64 + lane];

    half8 b0, b1;
    #pragma unroll
    for (int j = 0; j < 4; ++j) {
      ss0 += cur0[2 * j] * cur0[2 * j] + cur0[2 * j + 1] * cur0[2 * j + 1];
      ss1 += cur1[2 * j] * cur1[2 * j] + cur1[2 * j + 1] * cur1[2 * j + 1];
      fp16x2 h0 = __builtin_amdgcn_cvt_pkrtz(cur0[2 * j], cur0[2 * j + 1]);
      fp16x2 h1 = __builtin_amdgcn_cvt_pkrtz(cur1[2 * j], cur1[2 * j + 1]);
      b0[2 * j] = (_Float16)h0[0]; b0[2 * j + 1] = (_Float16)h0[1];
      b1[2 * j] = (_Float16)h1[0]; b1[2 * j + 1] = (_Float16)h1[1];
    }

    // SWAPPED operands: A = ft (rows=m), B = q (cols=n)  ->  D[m][n]
    acc[0][0] = __builtin_amdgcn_mfma_f32_16x16x32_f16(b0, a0, acc[0][0], 0, 0, 0);
    acc[1][0] = __builtin_amdgcn_mfma_f32_16x16x32_f16(b0, a1, acc[1][0], 0, 0, 0);
    acc[2][0] = __builtin_amdgcn_mfma_f32_16x16x32_f16(b0, a2, acc[2][0], 0, 0, 0);
    acc[3][0] = __builtin_amdgcn_mfma_f32_16x16x32_f16(b0, a3, acc[3][0], 0, 0, 0);
    acc[0][1] = __builtin_amdgcn_mfma_f32_16x16x32_f16(b1, a0, acc[0][1], 0, 0, 0);
    acc[1][1] = __builtin_amdgcn_mfma_f32_16x16x32_f16(b1, a1, acc[1][1], 0, 0, 0);
    acc[2][1] = __builtin_amdgcn_mfma_f32_16x16x32_f16(b1, a2, acc[2][1], 0, 0, 0);
    acc[3][1] = __builtin_amdgcn_mfma_f32_16x16x32_f16(b1, a3, acc[3][1], 0, 0, 0);

    #pragma unroll
    for (int j = 0; j < 8; ++j) { cur0[j] = nxt0[j]; cur1[j] = nxt1[j]; }
  }

  // full column sumsq (groups hold disjoint c-subsets) -> per-col total
  ss0 += __shfl_xor(ss0, 16); ss0 += __shfl_xor(ss0, 32);
  ss1 += __shfl_xor(ss1, 16); ss1 += __shfl_xor(ss1, 32);

  // lane's output m-rows are g*4+r (+ mt*16); fetch those columns' scales
  float sc0[4], sc1[4];
  #pragma unroll
  for (int r = 0; r < 4; ++r) {
    float t0 = __shfl(ss0, g * 4 + r, 16);
    float t1 = __shfl(ss1, g * 4 + r, 16);
    sc0[r] = 100.0f / fmaxf(sqrtf(t0), 1e-12f);   // 1/(||f||*T)
    sc1[r] = 100.0f / fmaxf(sqrtf(t1), 1e-12f);
  }

  #pragma unroll
  for (int nt = 0; nt < 4; ++nt) {
    int n = nt * 16 + col;           // this lane's n (fixed per lane)
    int t = trg_lds[n];
    float v[8];
    #pragma unroll
    for (int r = 0; r < 4; ++r) {
      v[r]     = acc[nt][0][r] * sc0[r];
      v[4 + r] = acc[nt][1][r] * sc1[r];
    }
    #pragma unroll
    for (int r = 0; r < 4; ++r) {     // m = m0 + mt*16 + g*4 + r
      if (t == m0 + g * 4 + r)      trgl[b * NN + n] = v[r];
      if (t == m0 + 16 + g * 4 + r) trgl[b * NN + n] = v[4 + r];
    }
    float mx = fmaxf(fmaxf(fmaxf(v[0], v[1]), fmaxf(v[2], v[3])),
                     fmaxf(fmaxf(v[4], v[5]), fmaxf(v[6], v[7])));
    mx = fmaxf(mx, __shfl_xor(mx, 16));
    mx = fmaxf(mx, __shfl_xor(mx, 32));
    float s = 0.f;
    #pragma unroll
    for (int j = 0; j < 8; ++j) s += __expf(v[j] - mx);
    s += __shfl_xor(s, 16);
    s += __shfl_xor(s, 32);
    if (g == 0) { pM[w * NN + n] = mx; pS[w * NN + n] = s; }
  }
  __syncthreads();

  if (tid < NN) {
    int n = tid;
    float gm = fmaxf(fmaxf(pM[n], pM[NN + n]), fmaxf(pM[2 * NN + n], pM[3 * NN + n]));
    float S = 0.f;
    #pragma unroll
    for (int ww = 0; ww < 4; ++ww)
      S += pS[ww * NN + n] * __expf(pM[ww * NN + n] - gm);
    partM[mc * (BB * NN) + b * NN + n] = gm;
    partS[mc * (BB * NN) + b * NN + n] = S;
  }
}

// ---------------- final: lse merge + nll + masked mean ------------------
__global__ void __launch_bounds__(256)
reduceFinal(const float* __restrict__ partM,
            const float* __restrict__ partS,
            const float* __restrict__ trgl,
            const void* __restrict__ maskp,
            const float* __restrict__ minfoF,
            const int* __restrict__ minfoI,
            float* __restrict__ out) {
  int tid = threadIdx.x;
  int p = blockIdx.x * 256 + tid;    // 8 blocks x 256 = 2048 points

  float gm = -1e30f, S = 0.f;
  #pragma unroll
  for (int c2 = 0; c2 < MCHUNKS; ++c2) {
    float mi = partM[c2 * (BB * NN) + p];
    float si = partS[c2 * (BB * NN) + p];
    float nm = fmaxf(gm, mi);
    S = S * __expf(gm - nm) + si * __expf(mi - nm);
    gm = nm;
  }
  float nll = gm + logf(S) - trgl[p];

  int layout = minfoI[1];
  const unsigned char* mb = (const unsigned char*)maskp;
  float mval;
  if (layout == 2) mval = ((const float*)maskp)[p];
  else if (layout == 0) mval = (float)mb[p];
  else mval = (float)((const int*)maskp)[p];

  float v = nll * mval;
  #pragma unroll
  for (int off = 32; off >= 1; off >>= 1) v += __shfl_xor(v, off);
  __shared__ float ps[4];
  int w = tid >> 6, lane = tid & 63;
  if (lane == 0) ps[w] = v;
  __syncthreads();
  if (tid == 0) {
    float s = ps[0] + ps[1] + ps[2] + ps[3];
    float cnt = minfoF[0];
    atomicAdd(out, s / fmaxf(cnt, 1.0f));
  }
}

extern "C" void kernel_launch(void* const* d_in, const int* in_sizes, int n_in,
                              void* d_out, int out_size, void* d_ws, size_t ws_size,
                              hipStream_t stream) {
  const float* fs   = (const float*)d_in[0];
  const float* ft   = (const float*)d_in[1];
  const float* ksrc = (const float*)d_in[2];
  const float* ktrg = (const float*)d_in[3];
  const void*  mask = d_in[4];
  float* out = (float*)d_out;

  _Float16* wq = (_Float16*)d_ws;                        // BB*16384 halfs
  float* partM = (float*)((char*)d_ws + (size_t)BB * 16384 * 2);
  float* partS = partM + (size_t)MCHUNKS * BB * NN;
  float* trgl  = partS + (size_t)MCHUNKS * BB * NN;
  int* tidx    = (int*)(trgl + BB * NN);
  float* minfoF = (float*)(tidx + BB * NN);
  int* minfoI   = (int*)minfoF;

  phase0_gather_norm<<<BB * NN, 256, 0, stream>>>(fs, ksrc, ktrg, mask, wq, tidx,
                                                  minfoF, minfoI, out);
  phaseB<<<NBLK, 256, 0, stream>>>(ft, wq, tidx, partM, partS, trgl);
  reduceFinal<<<BB * NN / 256, 256, 0, stream>>>(partM, partS, trgl, mask,
                                                 minfoF, minfoI, out);
}